// Round 1
// baseline (1997.301 us; speedup 1.0000x reference)
//
#include <hip/hip_runtime.h>
#include <hip/hip_fp16.h>
#include <stdint.h>

#define HH 256
#define WW 1216
#define BB 2
#define CC 64
#define IPIX (HH*WW)
#define NPIX (BB*IPIX)

typedef __attribute__((ext_vector_type(8))) __bf16 bf16x8;
typedef __attribute__((ext_vector_type(4))) __bf16 bf16x4;
typedef __attribute__((ext_vector_type(4))) float floatx4;
typedef __attribute__((ext_vector_type(4))) _Float16 half4;

__device__ __forceinline__ float sigm(float x) { return 1.f / (1.f + __expf(-x)); }

// layer order: aff7(24), aff5(16), aff3(8), att7(6), att5(6), att3(6), att1(6), mask(6)
constexpr int LSTART_H[9] = {0,24,40,48,54,60,66,72,78};

// 7x7 tap -> aff plane index (-1 = center, uses g1 with no aff factor)
constexpr int PLANE[49] = {
  0, 1, 2, 3, 4, 5, 6,
  7,24,25,26,27,28, 8,
  9,29,40,41,42,30,10,
 11,31,43,-1,44,32,12,
 13,33,45,46,47,34,14,
 15,35,36,37,38,39,16,
 17,18,19,20,21,22,23};
// 7x7 tap -> kernel class: 0='7', 1='5', 2='3', 3='1'
constexpr int KCLS[49] = {
 0,0,0,0,0,0,0,
 0,1,1,1,1,1,0,
 0,1,2,2,2,1,0,
 0,1,2,3,2,1,0,
 0,1,2,2,2,1,0,
 0,1,1,1,1,1,0,
 0,0,0,0,0,0,0};
// the 48 non-center taps in order
constexpr int TAPNC[48] = {
  0,1,2,3,4,5,6,7,8,9,10,11,12,13,14,15,16,17,18,19,20,21,22,23,
  25,26,27,28,29,30,31,32,33,34,35,36,37,38,39,40,41,42,43,44,45,46,47,48};

struct WPtrs {
    const float* w[8];
    const float* s[8];
    const float* b[8];
};

__device__ __forceinline__ void lds_fadd(float* p, float v) {
    __hip_atomic_fetch_add(p, v, __ATOMIC_RELAXED, __HIP_MEMORY_SCOPE_WORKGROUP);
}

// ---------------- K0: pack weights into MFMA A-fragment layout (bf16) ----------------
__global__ void k_pack(WPtrs wp, __bf16* __restrict__ wpk,
                       float* __restrict__ s_all, float* __restrict__ b_all) {
    int idx = blockIdx.x * blockDim.x + threadIdx.x;
    if (idx < 18 * 5 * 64) {
        int kk = idx / (5 * 64);
        int r = idx - kk * 5 * 64;
        int t = r >> 6, lane = r & 63;
        int m = t * 16 + (lane & 15);
        int L = 0, o = 0;
        bool valid_m = (m < 78);
        if (valid_m) {
            for (int i = 0; i < 8; i++) if (m >= LSTART_H[i]) { L = i; o = m - LSTART_H[i]; }
        }
        __bf16 vals[8];
        for (int j = 0; j < 8; j++) {
            int k = kk * 32 + ((lane >> 4) * 8) + j;
            int tap = k >> 6, c = k & 63;
            float w = valid_m ? wp.w[L][(o * 64 + c) * 9 + tap] : 0.f;
            vals[j] = (__bf16)w;
        }
        for (int j = 0; j < 8; j++) wpk[(size_t)idx * 8 + j] = vals[j];
    }
    if (idx < 80) {
        int m = idx;
        float sv = 0.f, bv = 0.f;
        if (m < 78) {
            int L = 0, o = 0;
            for (int i = 0; i < 8; i++) if (m >= LSTART_H[i]) { L = i; o = m - LSTART_H[i]; }
            sv = wp.s[L][o]; bv = wp.b[L][o];
        }
        s_all[m] = sv; b_all[m] = bv;
    }
}

// ---------------- K0c: feature fp32 NCHW -> bf16 (b,y,x,[c]) channel-packed ----------------
__global__ __launch_bounds__(256) void k_cvt(const float* __restrict__ feat,
                                             __bf16* __restrict__ fpk) {
    const int x = blockIdx.x * 64 + (threadIdx.x & 63);
    const int half = threadIdx.x >> 6;            // 0..3
    const int y = blockIdx.y, b = blockIdx.z;
    const float* fb = feat + (size_t)b * CC * IPIX + (size_t)y * WW + x;
    __bf16* op = fpk + ((size_t)(b * IPIX + y * WW + x) << 6);
#pragma unroll
    for (int h = 0; h < 2; h++) {
        const int cg = half + h * 4;              // channel group of 8
        bf16x8 pk;
#pragma unroll
        for (int j = 0; j < 8; j++) pk[j] = (__bf16)fb[(size_t)(cg * 8 + j) * IPIX];
        *(bf16x8*)(op + cg * 8) = pk;
    }
}

// ---------------- K1: conv as implicit GEMM; weights straight from L1/L2, no K-loop barriers ----
// Block: 256 thr = 4 waves; pixel tile 32 wide x 4 high; wave w = row w, 2 N-frags of 16.
// LDS: sh feature tile only = 29376 B -> 5 blocks/CU. wpk (92 KB) is L2-hot in every XCD;
// per-kk A-fragments read directly from global (coalesced 1 KB/instr), fully-unrolled loop
// lets the compiler pipeline loads across kk with zero barrier drains.
__global__ __launch_bounds__(256, 5) void k_conv(const __bf16* __restrict__ fpk,
        const float* __restrict__ d00, const __bf16* __restrict__ wpk,
        const float* __restrict__ s_all, const float* __restrict__ b_all,
        __bf16* __restrict__ afx, __bf16* __restrict__ attp, __bf16* __restrict__ maskp,
        float* __restrict__ stp) {
    __shared__ __bf16 sh[6 * 34 * 72];
    const int tid = threadIdx.x;
    // XCD-aware swizzle: contiguous y-slabs per XCD for halo L2 locality
    int flat = blockIdx.x + 38 * (blockIdx.y + 64 * blockIdx.z);
    int nf = (flat & 7) * 608 + (flat >> 3);
    int bx = nf % 38; int r2 = nf / 38;
    const int x0 = bx * 32, y0 = (r2 & 63) * 4, b = r2 >> 6;

    // stage feature tile from packed bf16: fully coalesced dwordx4 + ds_write_b128
    for (int idx = tid; idx < 204 * 8; idx += 256) {
        int cg = idx & 7, pos = idx >> 3;
        int row = pos / 34, x = pos - row * 34;
        int gy = y0 + row - 1, gx = x0 + x - 1;
        bf16x8 pk;
#pragma unroll
        for (int j = 0; j < 8; j++) pk[j] = (__bf16)0.f;
        if (gy >= 0 && gy < HH && gx >= 0 && gx < WW)
            pk = *(const bf16x8*)(fpk + ((size_t)(b * IPIX + gy * WW + gx) << 6) + cg * 8);
        *(bf16x8*)(sh + pos * 72 + cg * 8) = pk;
    }
    __syncthreads();

    const int wave = tid >> 6, lane = tid & 63;
    const int n = lane & 15, g = lane >> 4;

    floatx4 acc[5][2];
#pragma unroll
    for (int t = 0; t < 5; t++)
#pragma unroll
        for (int q = 0; q < 2; q++) acc[t][q] = (floatx4)(0.f);

#pragma unroll
    for (int kk = 0; kk < 18; kk++) {
        const int tap = kk >> 1;
        const int dy = tap / 3 - 1, dx = tap % 3 - 1;
        const int c0 = (kk & 1) * 32 + g * 8;
        bf16x8 bfr[2];
        const int rowb = wave + 1 + dy;
        const int colb = 1 + dx + n;
#pragma unroll
        for (int q = 0; q < 2; q++)
            bfr[q] = *(const bf16x8*)(sh + ((rowb * 34) + colb + q * 16) * 72 + c0);
        const __bf16* wb = wpk + (size_t)kk * 2560 + lane * 8;
        bf16x8 afr[5];
#pragma unroll
        for (int t = 0; t < 5; t++) afr[t] = *(const bf16x8*)(wb + t * 512);
#pragma unroll
        for (int t = 0; t < 5; t++)
#pragma unroll
            for (int q = 0; q < 2; q++)
                acc[t][q] = __builtin_amdgcn_mfma_f32_16x16x32_bf16(afr[t], bfr[q], acc[t][q], 0, 0, 0);
    }
    __syncthreads();   // sh feature reads done by ALL waves before phase-1 overwrites sh

    // phase 1: scale/bias + stats; bf16 results into LDS sh[m*132 + wave*32 + n + 16q]
    const int pix_base = b * IPIX + (y0 + wave) * WW + x0 + n;
    float p7[2] = {0,0}, t7[2] = {0,0};
    float p5[2] = {0,0}, t5[2] = {0,0};
    float p3[2] = {0,0}, t3[2] = {0,0};

#pragma unroll
    for (int t = 0; t < 5; t++) {
        const floatx4 sv = *(const floatx4*)(s_all + t * 16 + 4 * g);
        const floatx4 bv = *(const floatx4*)(b_all + t * 16 + 4 * g);
#pragma unroll
        for (int q = 0; q < 2; q++) {
#pragma unroll
            for (int reg = 0; reg < 4; reg++) {
                const int m = t * 16 + 4 * g + reg;
                const float v = fmaf(acc[t][q][reg], sv[reg], bv[reg]);
                if (m < 24)                { p7[q] += fabsf(v); t7[q] += v; }
                else if (m < 40)           { p5[q] += fabsf(v); t5[q] += v; }
                else if (m < 48)           { p3[q] += fabsf(v); t3[q] += v; }
                const float outv = (m < 48) ? v : sigm(v);
                sh[m * 132 + wave * 32 + n + q * 16] = (__bf16)outv;
            }
        }
    }
#pragma unroll
    for (int q = 0; q < 2; q++) {
        p7[q] += __shfl_xor(p7[q], 16); p7[q] += __shfl_xor(p7[q], 32);
        t7[q] += __shfl_xor(t7[q], 16); t7[q] += __shfl_xor(t7[q], 32);
        p5[q] += __shfl_xor(p5[q], 16); p5[q] += __shfl_xor(p5[q], 32);
        t5[q] += __shfl_xor(t5[q], 16); t5[q] += __shfl_xor(t5[q], 32);
        p3[q] += __shfl_xor(p3[q], 16); p3[q] += __shfl_xor(p3[q], 32);
        t3[q] += __shfl_xor(t3[q], 16); t3[q] += __shfl_xor(t3[q], 32);
    }
    if (g == 0) {
#pragma unroll
        for (int q = 0; q < 2; q++) {
            const int pixq = pix_base + q * 16;
            floatx4 s0 = {p7[q], p5[q], p3[q], t7[q]};
            floatx4 s1 = {t5[q], t3[q], 0.f, 0.f};
            *(floatx4*)(stp + (size_t)pixq * 8)     = s0;
            *(floatx4*)(stp + (size_t)pixq * 8 + 4) = s1;
        }
    }
    __syncthreads();

    // phase 2a: per-pixel tap-ordered aff pack: afx[pix][jj] = aff[PLANE[TAPNC[jj]]](pix)
    // 2 threads per pixel, 3x bf16x8 stores each -> contiguous 96 B per pixel
    {
        const int pxi = tid >> 1;                 // 0..127
        const int hf = tid & 1;                   // 0..1
        const int prow2 = pxi >> 5, pcol2 = pxi & 31;
        const int pix2 = b * IPIX + (y0 + prow2) * WW + x0 + pcol2;
#pragma unroll
        for (int k = 0; k < 3; k++) {
            bf16x8 v;
#pragma unroll
            for (int e = 0; e < 8; e++) {
                const int jj = hf * 24 + k * 8 + e;
                v[e] = sh[PLANE[TAPNC[jj]] * 132 + pxi];
            }
            *(bf16x8*)(afx + (size_t)pix2 * 48 + hf * 24 + k * 8) = v;
        }
    }

    // phase 2b: att/mask transpose-read, coalesced stores
    const int px = tid & 127;
    const int grp = tid >> 7;
    const int prow = px >> 5, pcol = px & 31;
    const int pix = b * IPIX + (y0 + prow) * WW + x0 + pcol;
    const float d00v = d00[pix];
    const float valid = (d00v > 0.f) ? 1.f : 0.f;
#pragma unroll
    for (int j = 0; j < 6; j += 2) {
        const int it = j + grp;
        bf16x4 av = { sh[(48 + it) * 132 + px], sh[(54 + it) * 132 + px],
                      sh[(60 + it) * 132 + px], sh[(66 + it) * 132 + px] };
        *(bf16x4*)(attp + ((size_t)it * NPIX + pix) * 4) = av;
        maskp[(size_t)it * NPIX + pix] = (__bf16)((float)sh[(72 + it) * 132 + px] * valid);
    }
}

// ---------------- K2 (once): per-pixel, per-iter guide ratios r_k and g0*d0 ----------------
__global__ __launch_bounds__(256) void k_rg(const __bf16* __restrict__ attp,
        const float* __restrict__ stp, const float* __restrict__ d0,
        _Float16* __restrict__ rp, float* __restrict__ gd) {
    int g = blockIdx.x * blockDim.x + threadIdx.x;
    if (g >= NPIX) return;
    const floatx4 s0 = *(const floatx4*)(stp + (size_t)g * 8);
    const floatx4 s1 = *(const floatx4*)(stp + (size_t)g * 8 + 4);
    const float S7 = s0[0], S5 = s0[1], S3 = s0[2], T7 = s0[3], T5 = s1[0], T3 = s1[1];
    const float d0v = d0[g];
#pragma unroll
    for (int it = 0; it < 6; it++) {
        bf16x4 a = *(const bf16x4*)(attp + ((size_t)it * NPIX + g) * 4);
        float a7 = (float)a[0], a5 = (float)a[1], a3 = (float)a[2], a1 = (float)a[3];
        float denom = a7 * S7 + a5 * S5 + a3 * S3 + a1;   // > 0: a1 = sigmoid > 0
        float inv = 1.f / denom;
        float r7 = a7 * inv, r5 = a5 * inv, r3 = a3 * inv, r1 = a1 * inv;
        float g0 = 1.f - (r7 * T7 + r5 * T5 + r3 * T3 + r1);
        half4 rv = {(_Float16)r7, (_Float16)r5, (_Float16)r3, (_Float16)r1};
        *(half4*)(rp + ((size_t)it * NPIX + g) * 4) = rv;
        gd[(size_t)it * NPIX + g] = g0 * d0v;
    }
}

// ---------------- K3 (per iter): SCATTER form. Every factor lane-local; afx streamed
// contiguously (96 B/pixel); contributions ds_add_f32'd into padded LDS acc tile.
// Tile: 32 x 16 outputs, input region 38 x 22 (halo 3), 256 threads.
__global__ __launch_bounds__(256) void k_iter(const _Float16* __restrict__ rp,
        const float* __restrict__ gd, const float* __restrict__ dt,
        const __bf16* __restrict__ afx, const __bf16* __restrict__ maskp,
        const float* __restrict__ d00,
        float* __restrict__ dtn, int it) {
    __shared__ float accs[28 * 44];    // [ly+i][lx+j], ly+i<=27, lx+j<=43
    const int tid = threadIdx.x;
    int flat = blockIdx.x + 38 * (blockIdx.y + 16 * blockIdx.z);
    int nf = (flat & 7) * 152 + (flat >> 3);
    int bx = nf % 38; int r2 = nf / 38;
    const int x0 = bx * 32, y0 = (r2 & 15) * 16, b = r2 >> 4;
    const int ib = b * IPIX;

    for (int idx = tid; idx < 28 * 44; idx += 256) accs[idx] = 0.f;
    __syncthreads();

    for (int idx = tid; idx < 22 * 38; idx += 256) {
        const int ly = idx / 38, lx = idx - ly * 38;
        const int gy = y0 + ly - 3, gx = x0 + lx - 3;
        if (gy >= 0 && gy < HH && gx >= 0 && gx < WW) {
            const int q = ib + gy * WW + gx;
            const half4 rv = *(const half4*)(rp + ((size_t)it * NPIX + q) * 4);
            const float dtv = dt[q];
            const float gdv = gd[(size_t)it * NPIX + q];
            float rc[4];
            rc[0] = (float)rv[0] * dtv; rc[1] = (float)rv[1] * dtv;
            rc[2] = (float)rv[2] * dtv; rc[3] = (float)rv[3] * dtv;
            bf16x8 A0 = *(const bf16x8*)(afx + (size_t)q * 48);
            bf16x8 A1 = *(const bf16x8*)(afx + (size_t)q * 48 + 8);
            bf16x8 A2 = *(const bf16x8*)(afx + (size_t)q * 48 + 16);
            bf16x8 A3 = *(const bf16x8*)(afx + (size_t)q * 48 + 24);
            bf16x8 A4 = *(const bf16x8*)(afx + (size_t)q * 48 + 32);
            bf16x8 A5 = *(const bf16x8*)(afx + (size_t)q * 48 + 40);
            float* abase = accs + ly * 44 + lx;
            // center tap t=24 (i=j=3): r1*dt + g0*d0
            lds_fadd(abase + 3 * 44 + 3, rc[3] + gdv);
#pragma unroll
            for (int jj = 0; jj < 48; jj++) {
                const int t = TAPNC[jj];
                const int i = t / 7, j = t % 7;
                float av;
                switch (jj >> 3) {
                    case 0: av = (float)A0[jj & 7]; break;
                    case 1: av = (float)A1[jj & 7]; break;
                    case 2: av = (float)A2[jj & 7]; break;
                    case 3: av = (float)A3[jj & 7]; break;
                    case 4: av = (float)A4[jj & 7]; break;
                    default: av = (float)A5[jj & 7]; break;
                }
                lds_fadd(abase + i * 44 + j, av * rc[KCLS[t]]);
            }
        }
    }
    __syncthreads();

    const int tx = tid & 31, ty = tid >> 5;     // ty 0..7, two output rows per thread
#pragma unroll
    for (int r = 0; r < 16; r += 8) {
        const int oy = ty + r;
        const int pix = ib + (y0 + oy) * WW + (x0 + tx);
        const float acc = accs[(oy + 6) * 44 + (tx + 6)];
        const float m = (float)maskp[(size_t)it * NPIX + pix];
        dtn[pix] = m * d00[pix] + (1.f - m) * acc;
    }
}

// ---------------- launch ----------------
extern "C" void kernel_launch(void* const* d_in, const int* in_sizes, int n_in,
                              void* d_out, int out_size, void* d_ws, size_t ws_size,
                              hipStream_t stream) {
    const float* feat = (const float*)d_in[0];
    const float* d0   = (const float*)d_in[1];
    const float* d00  = (const float*)d_in[2];
    WPtrs wp;
    for (int l = 0; l < 8; l++) {
        wp.w[l] = (const float*)d_in[3 + 3 * l];
        wp.s[l] = (const float*)d_in[4 + 3 * l];
        wp.b[l] = (const float*)d_in[5 + 3 * l];
    }
    __bf16*   wsb   = (__bf16*)d_ws;
    __bf16*   afx   = wsb;                                   // NPIX x 48 bf16, tap-ordered
    __bf16*   attp  = afx + (size_t)48 * NPIX;               // 6*NPIX bf16x4
    __bf16*   msk_b = attp + (size_t)24 * NPIX;              // 6 planes bf16
    float*    stp   = (float*)(msk_b + (size_t)6 * NPIX);    // NPIX*8 fp32
    float*    dtA   = stp + (size_t)8 * NPIX;                // 1 fp32 plane (ping)
    __bf16*   wpk   = (__bf16*)(dtA + (size_t)NPIX);         // 92160 B packed weights
    float*    s_all = (float*)(wpk + 18 * 5 * 64 * 8);
    float*    b_all = s_all + 80;
    // region X: fpk (dead after k_conv) aliased over rp+gd (written after, by k_rg)
    char*     X     = (char*)(b_all + 80);
    __bf16*   fpk   = (__bf16*)X;                            // 64*NPIX bf16 (79.7 MB)
    _Float16* rp    = (_Float16*)X;                          // 6*NPIX fp16x4
    float*    gd    = (float*)(X + (size_t)24 * NPIX * 2);   // 6*NPIX fp32
    float*    dtB   = (float*)d_out;                         // pong (overwritten before reads)

    hipLaunchKernelGGL(k_pack, dim3(23), dim3(256), 0, stream, wp, wpk, s_all, b_all);
    hipLaunchKernelGGL(k_cvt, dim3(WW / 64, HH, BB), dim3(256), 0, stream, feat, fpk);
    hipLaunchKernelGGL(k_conv, dim3(38, 64, 2), dim3(256), 0, stream,
                       fpk, d00, wpk, s_all, b_all, afx, attp, msk_b, stp);
    hipLaunchKernelGGL(k_rg, dim3(NPIX / 256), dim3(256), 0, stream,
                       attp, stp, d0, rp, gd);
    const float* cur = d0;
    for (int it = 0; it < 6; ++it) {
        float* nxt = (it & 1) ? dtB : dtA;
        if (it == 5) nxt = dtB;
        hipLaunchKernelGGL(k_iter, dim3(38, 16, 2), dim3(256), 0, stream,
                           rp, gd, cur, afx, msk_b, d00, nxt, it);
        cur = nxt;
    }
}

// Round 2
// 558.960 us; speedup vs baseline: 3.5732x; 3.5732x over previous
//
#include <hip/hip_runtime.h>
#include <hip/hip_fp16.h>
#include <stdint.h>

#define HH 256
#define WW 1216
#define BB 2
#define CC 64
#define IPIX (HH*WW)
#define NPIX (BB*IPIX)

typedef __attribute__((ext_vector_type(8))) __bf16 bf16x8;
typedef __attribute__((ext_vector_type(4))) __bf16 bf16x4;
typedef __attribute__((ext_vector_type(4))) float floatx4;
typedef __attribute__((ext_vector_type(4))) _Float16 half4;
typedef __attribute__((ext_vector_type(4))) uint32_t uint32x4;

__device__ __forceinline__ float sigm(float x) { return 1.f / (1.f + __expf(-x)); }

// layer order: aff7(24), aff5(16), aff3(8), att7(6), att5(6), att3(6), att1(6), mask(6)
constexpr int LSTART_H[9] = {0,24,40,48,54,60,66,72,78};

// 7x7 tap -> aff plane index (-1 = center, uses g1 with no aff factor)
constexpr int PLANE[49] = {
  0, 1, 2, 3, 4, 5, 6,
  7,24,25,26,27,28, 8,
  9,29,40,41,42,30,10,
 11,31,43,-1,44,32,12,
 13,33,45,46,47,34,14,
 15,35,36,37,38,39,16,
 17,18,19,20,21,22,23};
// 7x7 tap -> kernel class: 0='7', 1='5', 2='3', 3='1'
constexpr int KCLS[49] = {
 0,0,0,0,0,0,0,
 0,1,1,1,1,1,0,
 0,1,2,2,2,1,0,
 0,1,2,3,2,1,0,
 0,1,2,2,2,1,0,
 0,1,1,1,1,1,0,
 0,0,0,0,0,0,0};
// the 48 non-center taps in order
constexpr int TAPNC[48] = {
  0,1,2,3,4,5,6,7,8,9,10,11,12,13,14,15,16,17,18,19,20,21,22,23,
  25,26,27,28,29,30,31,32,33,34,35,36,37,38,39,40,41,42,43,44,45,46,47,48};

struct WPtrs {
    const float* w[8];
    const float* s[8];
    const float* b[8];
};

// ---------------- K0: pack weights into MFMA A-fragment layout (bf16) ----------------
__global__ void k_pack(WPtrs wp, __bf16* __restrict__ wpk,
                       float* __restrict__ s_all, float* __restrict__ b_all) {
    int idx = blockIdx.x * blockDim.x + threadIdx.x;
    if (idx < 18 * 5 * 64) {
        int kk = idx / (5 * 64);
        int r = idx - kk * 5 * 64;
        int t = r >> 6, lane = r & 63;
        int m = t * 16 + (lane & 15);
        int L = 0, o = 0;
        bool valid_m = (m < 78);
        if (valid_m) {
            for (int i = 0; i < 8; i++) if (m >= LSTART_H[i]) { L = i; o = m - LSTART_H[i]; }
        }
        __bf16 vals[8];
        for (int j = 0; j < 8; j++) {
            int k = kk * 32 + ((lane >> 4) * 8) + j;
            int tap = k >> 6, c = k & 63;
            float w = valid_m ? wp.w[L][(o * 64 + c) * 9 + tap] : 0.f;
            vals[j] = (__bf16)w;
        }
        for (int j = 0; j < 8; j++) wpk[(size_t)idx * 8 + j] = vals[j];
    }
    if (idx < 80) {
        int m = idx;
        float sv = 0.f, bv = 0.f;
        if (m < 78) {
            int L = 0, o = 0;
            for (int i = 0; i < 8; i++) if (m >= LSTART_H[i]) { L = i; o = m - LSTART_H[i]; }
            sv = wp.s[L][o]; bv = wp.b[L][o];
        }
        s_all[m] = sv; b_all[m] = bv;
    }
}

// ---------------- K0c: feature fp32 NCHW -> bf16 (b,y,x,[c]) channel-packed ----------------
__global__ __launch_bounds__(256) void k_cvt(const float* __restrict__ feat,
                                             __bf16* __restrict__ fpk) {
    const int x = blockIdx.x * 64 + (threadIdx.x & 63);
    const int half = threadIdx.x >> 6;            // 0..3
    const int y = blockIdx.y, b = blockIdx.z;
    const float* fb = feat + (size_t)b * CC * IPIX + (size_t)y * WW + x;
    __bf16* op = fpk + ((size_t)(b * IPIX + y * WW + x) << 6);
#pragma unroll
    for (int h = 0; h < 2; h++) {
        const int cg = half + h * 4;              // channel group of 8
        bf16x8 pk;
#pragma unroll
        for (int j = 0; j < 8; j++) pk[j] = (__bf16)fb[(size_t)(cg * 8 + j) * IPIX];
        *(bf16x8*)(op + cg * 8) = pk;
    }
}

// ---------------- K1: conv as implicit GEMM; weights LDS double-buffered (round-0 struct) ----
// Block: 256 thr = 4 waves; pixel tile 32 wide x 4 high; wave w = row w, 2 N-frags of 16.
// LDS: sh feature tile 29376 B + wlds weight dbuf 10240 B = 39616 B -> 4 blocks/CU.
__global__ __launch_bounds__(256, 4) void k_conv(const __bf16* __restrict__ fpk,
        const float* __restrict__ d00, const __bf16* __restrict__ wpk,
        const float* __restrict__ s_all, const float* __restrict__ b_all,
        __bf16* __restrict__ afx, __bf16* __restrict__ attp, __bf16* __restrict__ maskp,
        float* __restrict__ stp) {
    __shared__ __bf16 sh[6 * 34 * 72];
    __shared__ __bf16 wlds[2 * 2560];
    const int tid = threadIdx.x;
    // XCD-aware swizzle: contiguous y-slabs per XCD for halo L2 locality
    int flat = blockIdx.x + 38 * (blockIdx.y + 64 * blockIdx.z);
    int nf = (flat & 7) * 608 + (flat >> 3);
    int bx = nf % 38; int r2 = nf / 38;
    const int x0 = bx * 32, y0 = (r2 & 63) * 4, b = r2 >> 6;

    // prefetch weight panel 0 (5120 B)
    {
        bf16x8 w0 = *(const bf16x8*)(wpk + (size_t)tid * 8);
        *(bf16x8*)(wlds + tid * 8) = w0;
        if (tid < 64) {
            bf16x8 w1 = *(const bf16x8*)(wpk + 2048 + (size_t)tid * 8);
            *(bf16x8*)(wlds + 2048 + tid * 8) = w1;
        }
    }
    // stage feature tile from packed bf16: fully coalesced dwordx4 + ds_write_b128
    for (int idx = tid; idx < 204 * 8; idx += 256) {
        int cg = idx & 7, pos = idx >> 3;
        int row = pos / 34, x = pos - row * 34;
        int gy = y0 + row - 1, gx = x0 + x - 1;
        bf16x8 pk;
#pragma unroll
        for (int j = 0; j < 8; j++) pk[j] = (__bf16)0.f;
        if (gy >= 0 && gy < HH && gx >= 0 && gx < WW)
            pk = *(const bf16x8*)(fpk + ((size_t)(b * IPIX + gy * WW + gx) << 6) + cg * 8);
        *(bf16x8*)(sh + pos * 72 + cg * 8) = pk;
    }
    __syncthreads();

    const int wave = tid >> 6, lane = tid & 63;
    const int n = lane & 15, g = lane >> 4;

    floatx4 acc[5][2];
#pragma unroll
    for (int t = 0; t < 5; t++)
#pragma unroll
        for (int q = 0; q < 2; q++) acc[t][q] = (floatx4)(0.f);

#pragma unroll
    for (int kk = 0; kk < 18; kk++) {
        // prefetch weight panel kk+1 into registers (1-2 coalesced 16B loads/thread)
        bf16x8 wt0, wt1;
        if (kk < 17) {
            wt0 = *(const bf16x8*)(wpk + (size_t)(kk + 1) * 2560 + tid * 8);
            if (tid < 64) wt1 = *(const bf16x8*)(wpk + (size_t)(kk + 1) * 2560 + 2048 + tid * 8);
        }
        const int tap = kk >> 1;
        const int dy = tap / 3 - 1, dx = tap % 3 - 1;
        const int c0 = (kk & 1) * 32 + g * 8;
        bf16x8 bfr[2];
        const int rowb = wave + 1 + dy;
        const int colb = 1 + dx + n;
#pragma unroll
        for (int q = 0; q < 2; q++)
            bfr[q] = *(const bf16x8*)(sh + ((rowb * 34) + colb + q * 16) * 72 + c0);
        bf16x8 afr[5];
        const __bf16* wb = wlds + (kk & 1) * 2560 + lane * 8;
#pragma unroll
        for (int t = 0; t < 5; t++) afr[t] = *(const bf16x8*)(wb + t * 512);
#pragma unroll
        for (int t = 0; t < 5; t++)
#pragma unroll
            for (int q = 0; q < 2; q++)
                acc[t][q] = __builtin_amdgcn_mfma_f32_16x16x32_bf16(afr[t], bfr[q], acc[t][q], 0, 0, 0);
        if (kk < 17) {
            *(bf16x8*)(wlds + ((kk + 1) & 1) * 2560 + tid * 8) = wt0;
            if (tid < 64) *(bf16x8*)(wlds + ((kk + 1) & 1) * 2560 + 2048 + tid * 8) = wt1;
        }
        __syncthreads();
    }

    // phase 1: scale/bias + stats; bf16 results into LDS sh[m*132 + wave*32 + n + 16q]
    const int pix_base = b * IPIX + (y0 + wave) * WW + x0 + n;
    float p7[2] = {0,0}, t7[2] = {0,0};
    float p5[2] = {0,0}, t5[2] = {0,0};
    float p3[2] = {0,0}, t3[2] = {0,0};

#pragma unroll
    for (int t = 0; t < 5; t++) {
        const floatx4 sv = *(const floatx4*)(s_all + t * 16 + 4 * g);
        const floatx4 bv = *(const floatx4*)(b_all + t * 16 + 4 * g);
#pragma unroll
        for (int q = 0; q < 2; q++) {
#pragma unroll
            for (int reg = 0; reg < 4; reg++) {
                const int m = t * 16 + 4 * g + reg;
                const float v = fmaf(acc[t][q][reg], sv[reg], bv[reg]);
                if (m < 24)                { p7[q] += fabsf(v); t7[q] += v; }
                else if (m < 40)           { p5[q] += fabsf(v); t5[q] += v; }
                else if (m < 48)           { p3[q] += fabsf(v); t3[q] += v; }
                const float outv = (m < 48) ? v : sigm(v);
                sh[m * 132 + wave * 32 + n + q * 16] = (__bf16)outv;
            }
        }
    }
#pragma unroll
    for (int q = 0; q < 2; q++) {
        p7[q] += __shfl_xor(p7[q], 16); p7[q] += __shfl_xor(p7[q], 32);
        t7[q] += __shfl_xor(t7[q], 16); t7[q] += __shfl_xor(t7[q], 32);
        p5[q] += __shfl_xor(p5[q], 16); p5[q] += __shfl_xor(p5[q], 32);
        t5[q] += __shfl_xor(t5[q], 16); t5[q] += __shfl_xor(t5[q], 32);
        p3[q] += __shfl_xor(p3[q], 16); p3[q] += __shfl_xor(p3[q], 32);
        t3[q] += __shfl_xor(t3[q], 16); t3[q] += __shfl_xor(t3[q], 32);
    }
    if (g == 0) {
#pragma unroll
        for (int q = 0; q < 2; q++) {
            const int pixq = pix_base + q * 16;
            floatx4 s0 = {p7[q], p5[q], p3[q], t7[q]};
            floatx4 s1 = {t5[q], t3[q], 0.f, 0.f};
            *(floatx4*)(stp + (size_t)pixq * 8)     = s0;
            *(floatx4*)(stp + (size_t)pixq * 8 + 4) = s1;
        }
    }
    __syncthreads();

    // phase 2a: per-pixel tap-ordered aff pack: afx[pix][jj] = aff[PLANE[TAPNC[jj]]](pix)
    // 2 threads per pixel, 3x bf16x8 stores each -> contiguous 96 B per pixel
    {
        const int pxi = tid >> 1;                 // 0..127
        const int hf = tid & 1;                   // 0..1
        const int prow2 = pxi >> 5, pcol2 = pxi & 31;
        const int pix2 = b * IPIX + (y0 + prow2) * WW + x0 + pcol2;
#pragma unroll
        for (int k = 0; k < 3; k++) {
            bf16x8 v;
#pragma unroll
            for (int e = 0; e < 8; e++) {
                const int jj = hf * 24 + k * 8 + e;
                v[e] = sh[PLANE[TAPNC[jj]] * 132 + pxi];
            }
            *(bf16x8*)(afx + (size_t)pix2 * 48 + hf * 24 + k * 8) = v;
        }
    }

    // phase 2b: att/mask transpose-read, coalesced stores
    const int px = tid & 127;
    const int grp = tid >> 7;
    const int prow = px >> 5, pcol = px & 31;
    const int pix = b * IPIX + (y0 + prow) * WW + x0 + pcol;
    const float d00v = d00[pix];
    const float valid = (d00v > 0.f) ? 1.f : 0.f;
#pragma unroll
    for (int j = 0; j < 6; j += 2) {
        const int it = j + grp;
        bf16x4 av = { sh[(48 + it) * 132 + px], sh[(54 + it) * 132 + px],
                      sh[(60 + it) * 132 + px], sh[(66 + it) * 132 + px] };
        *(bf16x4*)(attp + ((size_t)it * NPIX + pix) * 4) = av;
        maskp[(size_t)it * NPIX + pix] = (__bf16)((float)sh[(72 + it) * 132 + px] * valid);
    }
}

// ---------------- K2 (once): per-pixel, per-iter guide ratios r_k and g0*d0 ----------------
__global__ __launch_bounds__(256) void k_rg(const __bf16* __restrict__ attp,
        const float* __restrict__ stp, const float* __restrict__ d0,
        _Float16* __restrict__ rp, float* __restrict__ gd) {
    int g = blockIdx.x * blockDim.x + threadIdx.x;
    if (g >= NPIX) return;
    const floatx4 s0 = *(const floatx4*)(stp + (size_t)g * 8);
    const floatx4 s1 = *(const floatx4*)(stp + (size_t)g * 8 + 4);
    const float S7 = s0[0], S5 = s0[1], S3 = s0[2], T7 = s0[3], T5 = s1[0], T3 = s1[1];
    const float d0v = d0[g];
#pragma unroll
    for (int it = 0; it < 6; it++) {
        bf16x4 a = *(const bf16x4*)(attp + ((size_t)it * NPIX + g) * 4);
        float a7 = (float)a[0], a5 = (float)a[1], a3 = (float)a[2], a1 = (float)a[3];
        float denom = a7 * S7 + a5 * S5 + a3 * S3 + a1;   // > 0: a1 = sigmoid > 0
        float inv = 1.f / denom;
        float r7 = a7 * inv, r5 = a5 * inv, r3 = a3 * inv, r1 = a1 * inv;
        float g0 = 1.f - (r7 * T7 + r5 * T5 + r3 * T3 + r1);
        half4 rv = {(_Float16)r7, (_Float16)r5, (_Float16)r3, (_Float16)r1};
        *(half4*)(rp + ((size_t)it * NPIX + g) * 4) = rv;
        gd[(size_t)it * NPIX + g] = g0 * d0v;
    }
}

// ---------------- K3 (per iter): gather via LDS-staged afx records + P-class planes ------
// Tile 32x8 outputs / 256 threads (1 output each); input region 38x14 = 532 pixels.
// LDS: sa32[532][25] afx records (stride 25 dwords, odd -> conflict-free u16 gather reads),
//      sps[4][536]  f32 planes: r7*dt, r5*dt, r3*dt, (r1*dt + g0*d0).
// No atomics, no global scatter; 48 (ds_read_u16 + ds_read_b32 + fmaf) per output with
// compile-time DS immediate offsets.
#define SPP 536
__global__ __launch_bounds__(256) void k_iter(const _Float16* __restrict__ rp,
        const float* __restrict__ gd, const float* __restrict__ dt,
        const __bf16* __restrict__ afx, const __bf16* __restrict__ maskp,
        const float* __restrict__ d00,
        float* __restrict__ dtn, int it) {
    __shared__ uint32_t sa32[532 * 25];   // 53200 B
    __shared__ float sps[4 * SPP];        // 8576 B
    const int tid = threadIdx.x;
    int flat = blockIdx.x + 38 * (blockIdx.y + 32 * blockIdx.z);
    int nf = (flat & 7) * 304 + (flat >> 3);
    int bx = nf % 38; int r2 = nf / 38;
    const int x0 = bx * 32, y0 = (r2 & 31) * 8, b = r2 >> 5;
    const int ib = b * IPIX;

    for (int idx = tid; idx < 532; idx += 256) {
        const int ly = idx / 38, lx = idx - ly * 38;
        const int gy = y0 + ly - 3, gx = x0 + lx - 3;
        uint32x4 A[6];
        float c0 = 0.f, c1 = 0.f, c2 = 0.f, c3 = 0.f;
        if (gy >= 0 && gy < HH && gx >= 0 && gx < WW) {
            const int q = ib + gy * WW + gx;
            const uint32_t* src = (const uint32_t*)(afx + (size_t)q * 48);
#pragma unroll
            for (int k = 0; k < 6; k++) A[k] = *(const uint32x4*)(src + k * 4);
            const half4 rv = *(const half4*)(rp + ((size_t)it * NPIX + q) * 4);
            const float dtv = dt[q];
            const float gdv = gd[(size_t)it * NPIX + q];
            c0 = (float)rv[0] * dtv; c1 = (float)rv[1] * dtv;
            c2 = (float)rv[2] * dtv; c3 = (float)rv[3] * dtv + gdv;
        } else {
#pragma unroll
            for (int k = 0; k < 6; k++) A[k] = (uint32x4)(0u);
        }
        uint32_t* d = sa32 + idx * 25;
#pragma unroll
        for (int k = 0; k < 6; k++) {
            d[k * 4 + 0] = A[k][0]; d[k * 4 + 1] = A[k][1];
            d[k * 4 + 2] = A[k][2]; d[k * 4 + 3] = A[k][3];
        }
        sps[idx] = c0; sps[SPP + idx] = c1; sps[2 * SPP + idx] = c2; sps[3 * SPP + idx] = c3;
    }
    __syncthreads();

    const int ox = tid & 31, oy = tid >> 5;     // 32x8 outputs
    const int pbase = oy * 38 + ox;             // p for tap (i=6, j=6)
    const __bf16* sab = (const __bf16*)sa32;
    float acc0 = sps[3 * SPP + pbase + 3 * 38 + 3];   // center: r1*dt + g0*d0
    float acc1 = 0.f;
#pragma unroll
    for (int jj = 0; jj < 48; jj++) {
        const int t = TAPNC[jj];
        const int i = t / 7, j = t % 7;
        const int off = (6 - i) * 38 + (6 - j);
        const float av = (float)sab[(pbase + off) * 50 + jj];
        const float pv = sps[KCLS[t] * SPP + pbase + off];
        if (jj & 1) acc1 = fmaf(av, pv, acc1);
        else        acc0 = fmaf(av, pv, acc0);
    }
    const float acc = acc0 + acc1;

    const int pix = ib + (y0 + oy) * WW + (x0 + ox);
    const float m = (float)maskp[(size_t)it * NPIX + pix];
    dtn[pix] = m * d00[pix] + (1.f - m) * acc;
}

// ---------------- launch ----------------
extern "C" void kernel_launch(void* const* d_in, const int* in_sizes, int n_in,
                              void* d_out, int out_size, void* d_ws, size_t ws_size,
                              hipStream_t stream) {
    const float* feat = (const float*)d_in[0];
    const float* d0   = (const float*)d_in[1];
    const float* d00  = (const float*)d_in[2];
    WPtrs wp;
    for (int l = 0; l < 8; l++) {
        wp.w[l] = (const float*)d_in[3 + 3 * l];
        wp.s[l] = (const float*)d_in[4 + 3 * l];
        wp.b[l] = (const float*)d_in[5 + 3 * l];
    }
    __bf16*   wsb   = (__bf16*)d_ws;
    __bf16*   afx   = wsb;                                   // NPIX x 48 bf16, tap-ordered
    __bf16*   attp  = afx + (size_t)48 * NPIX;               // 6*NPIX bf16x4
    __bf16*   msk_b = attp + (size_t)24 * NPIX;              // 6 planes bf16
    float*    stp   = (float*)(msk_b + (size_t)6 * NPIX);    // NPIX*8 fp32
    float*    dtA   = stp + (size_t)8 * NPIX;                // 1 fp32 plane (ping)
    __bf16*   wpk   = (__bf16*)(dtA + (size_t)NPIX);         // 92160 B packed weights
    float*    s_all = (float*)(wpk + 18 * 5 * 64 * 8);
    float*    b_all = s_all + 80;
    // region X: fpk (dead after k_conv) aliased over rp+gd (written after, by k_rg)
    char*     X     = (char*)(b_all + 80);
    __bf16*   fpk   = (__bf16*)X;                            // 64*NPIX bf16 (79.7 MB)
    _Float16* rp    = (_Float16*)X;                          // 6*NPIX fp16x4
    float*    gd    = (float*)(X + (size_t)24 * NPIX * 2);   // 6*NPIX fp32
    float*    dtB   = (float*)d_out;                         // pong (overwritten before reads)

    hipLaunchKernelGGL(k_pack, dim3(23), dim3(256), 0, stream, wp, wpk, s_all, b_all);
    hipLaunchKernelGGL(k_cvt, dim3(WW / 64, HH, BB), dim3(256), 0, stream, feat, fpk);
    hipLaunchKernelGGL(k_conv, dim3(38, 64, 2), dim3(256), 0, stream,
                       fpk, d00, wpk, s_all, b_all, afx, attp, msk_b, stp);
    hipLaunchKernelGGL(k_rg, dim3(NPIX / 256), dim3(256), 0, stream,
                       attp, stp, d0, rp, gd);
    const float* cur = d0;
    for (int it = 0; it < 6; ++it) {
        float* nxt = (it & 1) ? dtB : dtA;
        if (it == 5) nxt = dtB;
        hipLaunchKernelGGL(k_iter, dim3(38, 32, 2), dim3(256), 0, stream,
                           rp, gd, cur, afx, msk_b, d00, nxt, it);
        cur = nxt;
    }
}